// Round 1
// baseline (291.197 us; speedup 1.0000x reference)
//
#include <hip/hip_runtime.h>
#include <hip/hip_fp16.h>
#include <cmath>

#define DIM_M 1024   // B (batch)
#define DIM_K 8192   // D
#define DIM_N 4096   // U

typedef __attribute__((ext_vector_type(8))) _Float16 half8;
typedef __attribute__((ext_vector_type(4))) float floatx4;

struct __align__(8) Half4 { __half2 a, b; };

__device__ inline void gload_lds16(const void* g, void* l) {
    __builtin_amdgcn_global_load_lds(
        (const __attribute__((address_space(1))) void*)g,
        (__attribute__((address_space(3))) void*)l, 16, 0, 0);
}

__global__ void zero_f4(floatx4* __restrict__ p, int n4) {
    int i = blockIdx.x * blockDim.x + threadIdx.x;
    if (i < n4) p[i] = floatx4{0.f, 0.f, 0.f, 0.f};
}

// Wt[u*D + d] += v  (B^T layout [N][K]); duplicates add via HW fp32 atomic
__global__ void scatter_k(const int2* __restrict__ ind, const float* __restrict__ kv,
                          float* __restrict__ Wt, int nnz) {
    int i = blockIdx.x * blockDim.x + threadIdx.x;
    if (i < nnz) {
        int2 du = ind[i];                 // .x = d (row), .y = u (col)
        unsafeAtomicAdd(&Wt[(size_t)du.y * DIM_K + du.x], kv[i]);
    }
}

__global__ void cvt_f2h(const floatx4* __restrict__ in, Half4* __restrict__ out, int n4) {
    int i = blockIdx.x * blockDim.x + threadIdx.x;
    if (i < n4) {
        floatx4 f = in[i];
        Half4 h;
        h.a = __floats2half2_rn(f.x, f.y);
        h.b = __floats2half2_rn(f.z, f.w);
        out[i] = h;
    }
}

// C[M][N] = A[M][K] * B^T[N][K], epilogue tanh(c + bias[n]).
// 128x128 tile, BK=32, 4 waves (2x2), each wave 64x64 = 4x4 frags of 16x16x32 f16 MFMA.
template<bool BHALF>
__global__ __launch_bounds__(256) void gemm_k(
    const _Float16* __restrict__ Ah,   // [M][K] fp16
    const _Float16* __restrict__ Bh,   // [N][K] fp16 (if BHALF)
    const float*    __restrict__ Bf,   // [N][K] fp32 (if !BHALF)
    const float*    __restrict__ bias,
    float*          __restrict__ out)
{
    __shared__ _Float16 As[128 * 32];
    __shared__ _Float16 Bs[128 * 32];

    const int tid  = threadIdx.x;
    const int wave = tid >> 6;
    const int lane = tid & 63;
    const int n0 = blockIdx.x * 128;
    const int m0 = blockIdx.y * 128;
    const int wr = wave >> 1;          // wave row (0..1), 64 M-rows each
    const int wc = wave & 1;           // wave col (0..1), 64 N-cols each

    floatx4 acc[4][4] = {};

    // global_load_lds staging: lane's 16B lands at (wave-uniform base) + lane*16.
    // LDS byte w*2048 + c*1024 + lane*16 -> As row = w*32 + c*16 + lane/4, k = (lane&3)*8
    const _Float16* aS = Ah + (size_t)(m0 + wave * 32 + (lane >> 2)) * DIM_K + (lane & 3) * 8;
    _Float16* aL0 = &As[wave * 1024];
    _Float16* aL1 = &As[wave * 1024 + 512];

    const _Float16* bS = nullptr;
    if constexpr (BHALF)
        bS = Bh + (size_t)(n0 + wave * 32 + (lane >> 2)) * DIM_K + (lane & 3) * 8;

    for (int kt = 0; kt < DIM_K / 32; ++kt) {
        const int kk = kt * 32;
        gload_lds16(aS + kk, aL0);
        gload_lds16(aS + (size_t)16 * DIM_K + kk, aL1);
        if constexpr (BHALF) {
            gload_lds16(bS + kk, &Bs[wave * 1024]);
            gload_lds16(bS + (size_t)16 * DIM_K + kk, &Bs[wave * 1024 + 512]);
        } else {
            // reg-stage fp32 -> fp16: 128 rows x 32 k = 1024 float4s, 4 per thread
            #pragma unroll
            for (int p = 0; p < 4; ++p) {
                int idx = p * 256 + tid;
                int row = idx >> 3;          // 0..127
                int kq  = idx & 7;           // float4 index within row
                floatx4 f = *(const floatx4*)(Bf + (size_t)(n0 + row) * DIM_K + kk + kq * 4);
                Half4 h;
                h.a = __floats2half2_rn(f.x, f.y);
                h.b = __floats2half2_rn(f.z, f.w);
                *(Half4*)&Bs[row * 32 + kq * 4] = h;
            }
        }
        __syncthreads();   // drains vmcnt (global_load_lds) + lgkmcnt

        half8 aFr[4], bFr[4];
        #pragma unroll
        for (int mi = 0; mi < 4; ++mi)
            aFr[mi] = *(const half8*)&As[(wr * 64 + mi * 16 + (lane & 15)) * 32 + (lane >> 4) * 8];
        #pragma unroll
        for (int ni = 0; ni < 4; ++ni)
            bFr[ni] = *(const half8*)&Bs[(wc * 64 + ni * 16 + (lane & 15)) * 32 + (lane >> 4) * 8];
        #pragma unroll
        for (int mi = 0; mi < 4; ++mi)
            #pragma unroll
            for (int ni = 0; ni < 4; ++ni)
                acc[mi][ni] = __builtin_amdgcn_mfma_f32_16x16x32_f16(aFr[mi], bFr[ni], acc[mi][ni], 0, 0, 0);
        __syncthreads();
    }

    // Epilogue: C/D layout col = lane&15, row = (lane>>4)*4 + r  [m89-verified]
    #pragma unroll
    for (int ni = 0; ni < 4; ++ni) {
        const int col = n0 + wc * 64 + ni * 16 + (lane & 15);
        const float bv = bias[col];
        #pragma unroll
        for (int mi = 0; mi < 4; ++mi) {
            const int row = m0 + wr * 64 + mi * 16 + ((lane >> 4) << 2);
            #pragma unroll
            for (int r = 0; r < 4; ++r)
                out[(size_t)(row + r) * DIM_N + col] = tanhf(acc[mi][ni][r] + bv);
        }
    }
}

extern "C" void kernel_launch(void* const* d_in, const int* in_sizes, int n_in,
                              void* d_out, int out_size, void* d_ws, size_t ws_size,
                              hipStream_t stream) {
    const float* x    = (const float*)d_in[0];
    const float* kv   = (const float*)d_in[1];
    const float* bias = (const float*)d_in[2];
    const int2*  ind  = (const int2*)d_in[3];
    float* out = (float*)d_out;
    const int nnz = in_sizes[1];

    char* ws = (char*)d_ws;
    float* Wt = (float*)ws;                                   // [N][K] fp32, 128 MB
    const size_t wtBytes = (size_t)DIM_N * DIM_K * 4;
    _Float16* xh = (_Float16*)(ws + wtBytes);                 // [M][K] fp16, 16 MB
    const size_t xhBytes = (size_t)DIM_M * DIM_K * 2;
    _Float16* wh = (_Float16*)(ws + wtBytes + xhBytes);       // [N][K] fp16, 64 MB
    const size_t whBytes = (size_t)DIM_N * DIM_K * 2;
    const bool full = ws_size >= wtBytes + xhBytes + whBytes;

    const int wN4 = (int)((size_t)DIM_N * DIM_K / 4);   // 8388608
    const int xN4 = (int)((size_t)DIM_M * DIM_K / 4);   // 2097152

    zero_f4<<<(wN4 + 255) / 256, 256, 0, stream>>>((floatx4*)Wt, wN4);
    scatter_k<<<(nnz + 255) / 256, 256, 0, stream>>>(ind, kv, Wt, nnz);
    cvt_f2h<<<(xN4 + 255) / 256, 256, 0, stream>>>((const floatx4*)x, (Half4*)xh, xN4);

    dim3 grid(DIM_N / 128, DIM_M / 128);
    if (full) {
        cvt_f2h<<<(wN4 + 255) / 256, 256, 0, stream>>>((const floatx4*)Wt, (Half4*)wh, wN4);
        gemm_k<true><<<grid, 256, 0, stream>>>(xh, wh, nullptr, bias, out);
    } else {
        gemm_k<false><<<grid, 256, 0, stream>>>(xh, nullptr, Wt, bias, out);
    }
}

// Round 2
// 218.435 us; speedup vs baseline: 1.3331x; 1.3331x over previous
//
#include <hip/hip_runtime.h>
#include <hip/hip_fp16.h>
#include <cmath>

#define DIM_M 1024   // B (batch)
#define DIM_K 8192   // D
#define DIM_N 4096   // U
#define SPLIT 4
#define KSPL  (DIM_K / SPLIT)   // 2048

typedef __attribute__((ext_vector_type(8))) _Float16 half8;
typedef __attribute__((ext_vector_type(4))) float floatx4;

struct __align__(8) Half4 { __half2 a, b; };

__device__ inline void gload_lds16(const void* g, void* l) {
    __builtin_amdgcn_global_load_lds(
        (const __attribute__((address_space(1))) void*)g,
        (__attribute__((address_space(3))) void*)l, 16, 0, 0);
}

__global__ void zero_f4(floatx4* __restrict__ p, int n4) {
    int i = blockIdx.x * blockDim.x + threadIdx.x;
    if (i < n4) p[i] = floatx4{0.f, 0.f, 0.f, 0.f};
}

// scatter directly into fp16 W^T [N][K]: wh[u*K + d] += v via packed-f16 atomic
__global__ void scatter_h(const int2* __restrict__ ind, const float* __restrict__ kv,
                          __half2* __restrict__ wh2, int nnz) {
    int i = blockIdx.x * blockDim.x + threadIdx.x;
    if (i < nnz) {
        int2 du = ind[i];                                  // .x = d, .y = u
        size_t idx = (size_t)du.y * DIM_K + du.x;          // element in [N][K]
        __half hv = __float2half(kv[i]);
        __half z  = __float2half(0.0f);
        __half2 v = (idx & 1) ? __halves2half2(z, hv) : __halves2half2(hv, z);
        unsafeAtomicAdd(&wh2[idx >> 1], v);
    }
}

__global__ void cvt_f2h(const floatx4* __restrict__ in, Half4* __restrict__ out, int n4) {
    int i = blockIdx.x * blockDim.x + threadIdx.x;
    if (i < n4) {
        floatx4 f = in[i];
        Half4 h;
        h.a = __floats2half2_rn(f.x, f.y);
        h.b = __floats2half2_rn(f.z, f.w);
        out[i] = h;
    }
}

// Split-K GEMM: part[split][M][N] = A[M][kslice] * B^T[N][kslice]
// 128x128 tile, BK=32, 4 waves (2x2), 16x16x32 f16 MFMA, XOR-swizzled LDS.
__global__ __launch_bounds__(256) void gemm_k(
    const _Float16* __restrict__ Ah,   // [M][K] fp16
    const _Float16* __restrict__ Bh,   // [N][K] fp16
    float*          __restrict__ part) // [SPLIT][M][N] fp32
{
    __shared__ _Float16 As[128 * 32];
    __shared__ _Float16 Bs[128 * 32];

    const int tid  = threadIdx.x;
    const int wave = tid >> 6;
    const int lane = tid & 63;
    const int n0 = blockIdx.x * 128;
    const int m0 = blockIdx.y * 128;
    const int split = blockIdx.z;
    const size_t kbase = (size_t)split * KSPL;
    const int wr = wave >> 1;
    const int wc = wave & 1;

    floatx4 acc[4][4] = {};

    // Staging swizzle: lane loads global 16B-chunk (lane&3)^((lane>>3)&3) of its row;
    // LDS stays linear (gload_lds writes base+lane*16). Permutation stays within one
    // 64B line -> coalescing preserved. Read side applies the same involution.
    const int cg = ((lane & 3) ^ ((lane >> 3) & 3)) * 8;
    const _Float16* aS = Ah + (size_t)(m0 + wave * 32 + (lane >> 2)) * DIM_K + kbase + cg;
    const _Float16* bS = Bh + (size_t)(n0 + wave * 32 + (lane >> 2)) * DIM_K + kbase + cg;
    _Float16* aL0 = &As[wave * 1024];
    _Float16* aL1 = &As[wave * 1024 + 512];
    _Float16* bL0 = &Bs[wave * 1024];
    _Float16* bL1 = &Bs[wave * 1024 + 512];

    // Read-side swizzle: global chunk (lane>>4) of row r lives at LDS chunk
    // (lane>>4) ^ ((r>>1)&3); here (r>>1)&3 == (lane>>1)&3.
    const int rc = ((lane >> 4) ^ ((lane >> 1) & 3)) * 8;

    for (int kt = 0; kt < KSPL / 32; ++kt) {
        const int kk = kt * 32;
        gload_lds16(aS + kk, aL0);
        gload_lds16(aS + (size_t)16 * DIM_K + kk, aL1);
        gload_lds16(bS + kk, bL0);
        gload_lds16(bS + (size_t)16 * DIM_K + kk, bL1);
        __syncthreads();   // drains vmcnt (global_load_lds)

        half8 aFr[4], bFr[4];
        #pragma unroll
        for (int mi = 0; mi < 4; ++mi)
            aFr[mi] = *(const half8*)&As[(wr * 64 + mi * 16 + (lane & 15)) * 32 + rc];
        #pragma unroll
        for (int ni = 0; ni < 4; ++ni)
            bFr[ni] = *(const half8*)&Bs[(wc * 64 + ni * 16 + (lane & 15)) * 32 + rc];
        #pragma unroll
        for (int mi = 0; mi < 4; ++mi)
            #pragma unroll
            for (int ni = 0; ni < 4; ++ni)
                acc[mi][ni] = __builtin_amdgcn_mfma_f32_16x16x32_f16(aFr[mi], bFr[ni], acc[mi][ni], 0, 0, 0);
        __syncthreads();
    }

    // Store raw partials (C/D layout: col = lane&15, row = (lane>>4)*4 + r)
    float* pbase = part + (size_t)split * DIM_M * DIM_N;
    #pragma unroll
    for (int ni = 0; ni < 4; ++ni) {
        const int col = n0 + wc * 64 + ni * 16 + (lane & 15);
        #pragma unroll
        for (int mi = 0; mi < 4; ++mi) {
            const int row = m0 + wr * 64 + mi * 16 + ((lane >> 4) << 2);
            #pragma unroll
            for (int r = 0; r < 4; ++r)
                pbase[(size_t)(row + r) * DIM_N + col] = acc[mi][ni][r];
        }
    }
}

// out = tanh(sum_splits(part) + bias), vectorized float4
__global__ void reduce_tanh(const floatx4* __restrict__ part, const float* __restrict__ bias,
                            floatx4* __restrict__ out) {
    const int n4 = DIM_M * DIM_N / 4;
    int i = blockIdx.x * blockDim.x + threadIdx.x;
    if (i < n4) {
        floatx4 s = part[i];
        #pragma unroll
        for (int sp = 1; sp < SPLIT; ++sp)
            s += part[(size_t)sp * n4 + i];
        floatx4 b = ((const floatx4*)bias)[i & (DIM_N / 4 - 1)];
        floatx4 o;
        o.x = tanhf(s.x + b.x);
        o.y = tanhf(s.y + b.y);
        o.z = tanhf(s.z + b.z);
        o.w = tanhf(s.w + b.w);
        out[i] = o;
    }
}

extern "C" void kernel_launch(void* const* d_in, const int* in_sizes, int n_in,
                              void* d_out, int out_size, void* d_ws, size_t ws_size,
                              hipStream_t stream) {
    const float* x    = (const float*)d_in[0];
    const float* kv   = (const float*)d_in[1];
    const float* bias = (const float*)d_in[2];
    const int2*  ind  = (const int2*)d_in[3];
    float* out = (float*)d_out;
    const int nnz = in_sizes[1];

    char* ws = (char*)d_ws;
    _Float16* wh = (_Float16*)ws;                               // [N][K] fp16, 64 MB
    const size_t whBytes = (size_t)DIM_N * DIM_K * 2;
    _Float16* xh = (_Float16*)(ws + whBytes);                   // [M][K] fp16, 16 MB
    const size_t xhBytes = (size_t)DIM_M * DIM_K * 2;
    float* part = (float*)(ws + whBytes + xhBytes);             // [SPLIT][M][N] fp32, 67 MB

    const int wN4h = (int)(whBytes / 16);               // fp16 W zero-fill, 16B units
    const int xN4  = (int)((size_t)DIM_M * DIM_K / 4);  // x float4 count
    const int oN4  = DIM_M * DIM_N / 4;

    zero_f4<<<(wN4h + 255) / 256, 256, 0, stream>>>((floatx4*)wh, wN4h);
    cvt_f2h<<<(xN4 + 255) / 256, 256, 0, stream>>>((const floatx4*)x, (Half4*)xh, xN4);
    scatter_h<<<(nnz + 255) / 256, 256, 0, stream>>>(ind, kv, (__half2*)wh, nnz);

    dim3 grid(DIM_N / 128, DIM_M / 128, SPLIT);
    gemm_k<<<grid, 256, 0, stream>>>(xh, wh, part);

    reduce_tanh<<<(oN4 + 255) / 256, 256, 0, stream>>>((const floatx4*)part, bias, (floatx4*)out);
}

// Round 3
// 191.375 us; speedup vs baseline: 1.5216x; 1.1414x over previous
//
#include <hip/hip_runtime.h>
#include <hip/hip_fp16.h>
#include <cmath>

#define DIM_M 1024   // B (batch)
#define DIM_K 8192   // D
#define DIM_N 4096   // U
#define SPLIT 4
#define KSPL  (DIM_K / SPLIT)   // 2048
#define BKT   64
#define NT    (KSPL / BKT)      // 32 K-tiles per block

typedef __attribute__((ext_vector_type(8))) _Float16 half8;
typedef __attribute__((ext_vector_type(4))) float floatx4;

struct __align__(8) Half4 { __half2 a, b; };

__device__ inline void gload_lds16(const void* g, void* l) {
    __builtin_amdgcn_global_load_lds(
        (const __attribute__((address_space(1))) void*)g,
        (__attribute__((address_space(3))) void*)l, 16, 0, 0);
}

__global__ void zero_f4(floatx4* __restrict__ p, int n4) {
    int i = blockIdx.x * blockDim.x + threadIdx.x;
    if (i < n4) p[i] = floatx4{0.f, 0.f, 0.f, 0.f};
}

// scatter directly into fp16 W^T [N][K]: wh[u*K + d] += v via packed-f16 atomic
__global__ void scatter_h(const int2* __restrict__ ind, const float* __restrict__ kv,
                          __half2* __restrict__ wh2, int nnz) {
    int i = blockIdx.x * blockDim.x + threadIdx.x;
    if (i < nnz) {
        int2 du = ind[i];                                  // .x = d, .y = u
        size_t idx = (size_t)du.y * DIM_K + du.x;          // element in [N][K]
        __half hv = __float2half(kv[i]);
        __half z  = __float2half(0.0f);
        __half2 v = (idx & 1) ? __halves2half2(z, hv) : __halves2half2(hv, z);
        unsafeAtomicAdd(&wh2[idx >> 1], v);
    }
}

__global__ void cvt_f2h(const floatx4* __restrict__ in, Half4* __restrict__ out, int n4) {
    int i = blockIdx.x * blockDim.x + threadIdx.x;
    if (i < n4) {
        floatx4 f = in[i];
        Half4 h;
        h.a = __floats2half2_rn(f.x, f.y);
        h.b = __floats2half2_rn(f.z, f.w);
        out[i] = h;
    }
}

// ---------------------------------------------------------------------------
// 256x256 8-phase split-K GEMM: part[split][M][N] = A[M][ksl] * B^T[N][ksl]
// 512 thr (8 waves, 2M x 4N), BK=64, dbuf at K-tile level, counted vmcnt(8).
// LDS (dynamic 128KB): buf c: A[256][64]f16 @ c*65536, B[256][64]f16 @ +32768.
// Swizzle: logical 16B-chunk c of row r lives at physical chunk c ^ (r&7);
// applied on the pre-swizzled global source (write side, linear gload_lds
// dest) AND on the ds_read address (read side) — same involution.
// ---------------------------------------------------------------------------
__global__ __launch_bounds__(512, 2) void gemm8_k(
    const _Float16* __restrict__ Ah,   // [M][K] fp16
    const _Float16* __restrict__ Bh,   // [N][K] fp16
    float*          __restrict__ part) // [SPLIT][M][N] fp32
{
    extern __shared__ char smem[];

    const int tid  = threadIdx.x;
    const int lane = tid & 63;
    const int wave = tid >> 6;

    // chunked XCD swizzle (256 blocks, 8 XCDs -> 32 consecutive per XCD):
    // swz layout: n-tile (16) outer, then m-tile (4), split (4).
    const int bid = blockIdx.x;
    const int swz = (bid & 7) * 32 + (bid >> 3);
    const int n0  = (swz >> 4) * 256;
    const int rem = swz & 15;
    const int m0  = (rem >> 2) * 256;
    const int sp  = rem & 3;
    const size_t kbase = (size_t)sp * KSPL;

    // --- staging (write side): thread tid covers LDS row srow+j*64, chunk tid&7;
    // global source chunk pre-swizzled by ^(row&7) = ^(srow&7).
    const int srow = tid >> 3;                   // 0..63
    const int sch  = (tid & 7) ^ (srow & 7);
    const _Float16* aSg = Ah + (size_t)(m0 + srow) * DIM_K + kbase + sch * 8;
    const _Float16* bSg = Bh + (size_t)(n0 + srow) * DIM_K + kbase + sch * 8;
    char* aLg = smem + wave * 1024;
    char* bLg = smem + 32768 + wave * 1024;

    // --- read side: A rows wrm*128 + mi*16 + (lane&15); B rows wn*64 + ni*16 + (lane&15).
    // logical chunk = kk*4 + (lane>>4); XOR term (row&7) == (lane&7) (row offsets = 0 mod 16).
    const int wn  = wave & 3;
    const int wrm = wave >> 2;
    const int q   = lane >> 4;
    const int l7  = lane & 7;
    const char* aRd = smem + (wrm * 128 + (lane & 15)) * 128;
    const char* bRd = smem + 32768 + (wn * 64 + (lane & 15)) * 128;
    const int ch0 = ((0 * 4 + q) ^ l7) * 16;     // kk = 0
    const int ch1 = ((1 * 4 + q) ^ l7) * 16;     // kk = 1

    floatx4 acc[8][4] = {};
    half8 aF[4], bF[4];

#define STAGE(C)                                                              \
    { _Pragma("unroll") for (int j = 0; j < 4; ++j) {                         \
        gload_lds16(aSg + (size_t)j * (64 * DIM_K), aLg + (C) * 65536 + j * 8192); \
        gload_lds16(bSg + (size_t)j * (64 * DIM_K), bLg + (C) * 65536 + j * 8192); } \
      aSg += BKT; bSg += BKT; }

#define PH(C, MIOFF, CH, RB)                                                  \
    { _Pragma("unroll") for (int i = 0; i < 4; ++i)                           \
        aF[i] = *(const half8*)(aRd + (C) * 65536 + ((MIOFF) + i) * 2048 + (CH)); \
      if (RB) { _Pragma("unroll") for (int i = 0; i < 4; ++i)                 \
        bF[i] = *(const half8*)(bRd + (C) * 65536 + i * 2048 + (CH)); }       \
      __builtin_amdgcn_s_barrier();                                           \
      asm volatile("s_waitcnt lgkmcnt(0)" ::: "memory");                      \
      __builtin_amdgcn_sched_barrier(0);                                      \
      __builtin_amdgcn_s_setprio(1);                                          \
      _Pragma("unroll") for (int mi = 0; mi < 4; ++mi)                        \
        _Pragma("unroll") for (int ni = 0; ni < 4; ++ni)                      \
          acc[(MIOFF) + mi][ni] = __builtin_amdgcn_mfma_f32_16x16x32_f16(     \
              aF[mi], bF[ni], acc[(MIOFF) + mi][ni], 0, 0, 0);                \
      __builtin_amdgcn_s_setprio(0);                                          \
      __builtin_amdgcn_s_barrier(); }

#define KTILE(C) PH(C, 0, ch0, 1) PH(C, 4, ch0, 0) PH(C, 0, ch1, 1) PH(C, 4, ch1, 0)

    // prologue: stage K-tiles 0,1; wait for K-tile 0 (8 newest may fly)
    STAGE(0)
    STAGE(1)
    asm volatile("s_waitcnt vmcnt(8)" ::: "memory");
    __builtin_amdgcn_s_barrier();

    for (int t2 = 0; t2 < NT / 2; ++t2) {
        KTILE(0)                                  // compute K-tile 2*t2
        if (t2 < NT / 2 - 1) {
            STAGE(0)                              // stage K-tile 2*t2+2 into freed buf0
            asm volatile("s_waitcnt vmcnt(8)" ::: "memory");  // K-tile 2*t2+1 landed
        } else {
            asm volatile("s_waitcnt vmcnt(0)" ::: "memory");  // final: drain for last tile
        }
        __builtin_amdgcn_s_barrier();
        KTILE(1)                                  // compute K-tile 2*t2+1
        if (t2 < NT / 2 - 1) {
            STAGE(1)                              // stage K-tile 2*t2+3 into freed buf1
            asm volatile("s_waitcnt vmcnt(8)" ::: "memory");  // K-tile 2*t2+2 landed
            __builtin_amdgcn_s_barrier();
        }
    }

#undef KTILE
#undef PH
#undef STAGE

    // epilogue: raw partials (C/D layout: col = lane&15, row = q*4 + r)
    float* pbase = part + (size_t)sp * DIM_M * DIM_N;
    #pragma unroll
    for (int ni = 0; ni < 4; ++ni) {
        const int col = n0 + wn * 64 + ni * 16 + (lane & 15);
        #pragma unroll
        for (int mi = 0; mi < 8; ++mi) {
            const int row = m0 + wrm * 128 + mi * 16 + (q << 2);
            #pragma unroll
            for (int r = 0; r < 4; ++r)
                pbase[(size_t)(row + r) * DIM_N + col] = acc[mi][ni][r];
        }
    }
}

// out = tanh(sum_splits(part) + bias), vectorized float4
__global__ void reduce_tanh(const floatx4* __restrict__ part, const float* __restrict__ bias,
                            floatx4* __restrict__ out) {
    const int n4 = DIM_M * DIM_N / 4;
    int i = blockIdx.x * blockDim.x + threadIdx.x;
    if (i < n4) {
        floatx4 s = part[i];
        #pragma unroll
        for (int sp = 1; sp < SPLIT; ++sp)
            s += part[(size_t)sp * n4 + i];
        floatx4 b = ((const floatx4*)bias)[i & (DIM_N / 4 - 1)];
        floatx4 o;
        o.x = tanhf(s.x + b.x);
        o.y = tanhf(s.y + b.y);
        o.z = tanhf(s.z + b.z);
        o.w = tanhf(s.w + b.w);
        out[i] = o;
    }
}

extern "C" void kernel_launch(void* const* d_in, const int* in_sizes, int n_in,
                              void* d_out, int out_size, void* d_ws, size_t ws_size,
                              hipStream_t stream) {
    const float* x    = (const float*)d_in[0];
    const float* kv   = (const float*)d_in[1];
    const float* bias = (const float*)d_in[2];
    const int2*  ind  = (const int2*)d_in[3];
    float* out = (float*)d_out;
    const int nnz = in_sizes[1];

    char* ws = (char*)d_ws;
    _Float16* wh = (_Float16*)ws;                               // [N][K] fp16, 64 MB
    const size_t whBytes = (size_t)DIM_N * DIM_K * 2;
    _Float16* xh = (_Float16*)(ws + whBytes);                   // [M][K] fp16, 16 MB
    const size_t xhBytes = (size_t)DIM_M * DIM_K * 2;
    float* part = (float*)(ws + whBytes + xhBytes);             // [SPLIT][M][N] fp32, 64 MB

    const int wN4h = (int)(whBytes / 16);               // fp16 W zero-fill, 16B units
    const int xN4  = (int)((size_t)DIM_M * DIM_K / 4);  // x float4 count
    const int oN4  = DIM_M * DIM_N / 4;

    zero_f4<<<(wN4h + 255) / 256, 256, 0, stream>>>((floatx4*)wh, wN4h);
    cvt_f2h<<<(xN4 + 255) / 256, 256, 0, stream>>>((const floatx4*)x, (Half4*)xh, xN4);
    scatter_h<<<(nnz + 255) / 256, 256, 0, stream>>>(ind, kv, (__half2*)wh, nnz);

    hipFuncSetAttribute((const void*)gemm8_k,
                        hipFuncAttributeMaxDynamicSharedMemorySize, 131072);
    gemm8_k<<<dim3(256), 512, 131072, stream>>>(xh, wh, part);

    reduce_tanh<<<(oN4 + 255) / 256, 256, 0, stream>>>((const floatx4*)part, bias, (floatx4*)out);
}